// Round 1
// baseline (996.280 us; speedup 1.0000x reference)
//
#include <hip/hip_runtime.h>

namespace {

constexpr int H = 1024;
constexpr int W = 1024;
constexpr int PLANE = H * W;
constexpr int CIN = 18;     // total input channels
constexpr int C = 8;        // filterable channels
constexpr int TX = 16;
constexpr int TY = 16;
constexpr int SW = TX + 6;  // 22 halo tile width
constexpr int SH = TY + 6;  // 22 halo tile height
constexpr int NPOS = SW * SH;  // 484 positions
constexpr float LOG2E = 1.44269504088896340736f;

typedef _Float16 half2_t __attribute__((ext_vector_type(2)));
typedef _Float16 half8_t __attribute__((ext_vector_type(8)));

__device__ __forceinline__ float dot2acc(half2_t a, half2_t b, float c) {
#if defined(__has_builtin)
#if __has_builtin(__builtin_amdgcn_fdot2)
    return __builtin_amdgcn_fdot2(a, b, c, false);
#else
    return fmaf((float)a[0], (float)b[0], fmaf((float)a[1], (float)b[1], c));
#endif
#else
    return fmaf((float)a[0], (float)b[0], fmaf((float)a[1], (float)b[1], c));
#endif
}

__device__ __forceinline__ float fast_exp2(float x) {
#if defined(__has_builtin)
#if __has_builtin(__builtin_amdgcn_exp2f)
    return __builtin_amdgcn_exp2f(x);
#else
    return exp2f(x);
#endif
#else
    return exp2f(x);
#endif
}

template<bool INTERIOR>
__device__ __forceinline__ void run_tile(const float* __restrict__ inb,
                                         float* __restrict__ outb,
                                         half8_t* __restrict__ tile,
                                         float* __restrict__ msk,
                                         int gy0, int gx0)
{
    const int tx = threadIdx.x, ty = threadIdx.y;
    const int tid = ty * TX + tx;

    const int gy = gy0 + ty, gx = gx0 + tx;
    const int pofs = gy * W + gx;

    // ---- per-pixel params FIRST (before the barrier) so their global
    // latency overlaps the staging loop + barrier wait. log2e folded in.
    half2_t rp01, rp23, rp45, rp67;
    float sxf, syf;
    {
        const float* pp = inb + (size_t)C * PLANE + pofs;
        float r[C];
#pragma unroll
        for (int c = 0; c < C; ++c) {
            float p = pp[(size_t)c * PLANE];
            r[c] = -(p * p) * LOG2E;
        }
        float px_ = pp[(size_t)8 * PLANE];
        float py_ = pp[(size_t)9 * PLANE];
        rp01 = half2_t{(_Float16)r[0], (_Float16)r[1]};
        rp23 = half2_t{(_Float16)r[2], (_Float16)r[3]};
        rp45 = half2_t{(_Float16)r[4], (_Float16)r[5]};
        rp67 = half2_t{(_Float16)r[6], (_Float16)r[7]};
        sxf = -(px_ * px_) * LOG2E;
        syf = -(py_ * py_) * LOG2E;
    }

    // ---- stage: one 16B packed-f16 record per halo position ----
    for (int idx = tid; idx < NPOS; idx += TX * TY) {
        int y = idx / SW;
        int x = idx - y * SW;
        int sy_ = gy0 + y - 3;
        int sx_ = gx0 + x - 3;
        half8_t hv;
        if (INTERIOR || ((unsigned)sy_ < (unsigned)H && (unsigned)sx_ < (unsigned)W)) {
            const float* p = inb + sy_ * W + sx_;
#pragma unroll
            for (int c = 0; c < C; ++c) hv[c] = (_Float16)p[(size_t)c * PLANE];
            if (!INTERIOR) msk[idx] = 1.0f;
        } else {
#pragma unroll
            for (int c = 0; c < C; ++c) hv[c] = (_Float16)0.0f;
            msk[idx] = 0.0f;
        }
        tile[idx] = hv;
    }
    __syncthreads();

    const half8_t* lp = tile + ty * SW + tx;  // window origin for this pixel
    const half8_t fc = lp[3 * SW + 3];        // center (f16, so d==0 exactly)

    // precomputed per-row spatial seed: syf * dy^2  (7 regs, f32)
    float rowseed[7];
#pragma unroll
    for (int i = 0; i < 7; ++i)
        rowseed[i] = syf * (float)((i - 3) * (i - 3));

    // ---- software-pipelined rows: prefetch row i+1 (7x ds_read_b128 in
    // flight) while computing row i. Ping-pong buffer, all indices static
    // after full unroll (rule #20).
    half8_t buf[2][7];
#pragma unroll
    for (int j = 0; j < 7; ++j) buf[0][j] = lp[j];

    float acc0 = 0.f, acc1 = 0.f, acc2 = 0.f, ws = 0.f;
#pragma unroll
    for (int i = 0; i < 7; ++i) {
        // issue next row's loads before consuming current row
        if (i < 6) {
#pragma unroll
            for (int j = 0; j < 7; ++j)
                buf[(i + 1) & 1][j] = lp[(i + 1) * SW + j];
        }
        const float* mrow = msk + (ty + i) * SW + tx;
#pragma unroll
        for (int j = 0; j < 7; ++j) {
            half8_t q = buf[i & 1][j];
            half8_t d = q - fc;                 // 4x v_pk_add_f16
            half8_t dd = d * d;                 // 4x v_pk_mul_f16
            // spatial seed: sx*dx^2 + sy*dy^2 as one fma off the row seed
            float lw = fmaf((float)((j - 3) * (j - 3)), sxf, rowseed[i]);
            lw = dot2acc(__builtin_shufflevector(dd, dd, 0, 1), rp01, lw);
            lw = dot2acc(__builtin_shufflevector(dd, dd, 2, 3), rp23, lw);
            lw = dot2acc(__builtin_shufflevector(dd, dd, 4, 5), rp45, lw);
            lw = dot2acc(__builtin_shufflevector(dd, dd, 6, 7), rp67, lw);
            float w = fast_exp2(lw);
            if (!INTERIOR) w *= mrow[j];        // padding mask
            ws += w;
            acc0 = fmaf(w, (float)q[0], acc0);  // v_fma_mix_f32
            acc1 = fmaf(w, (float)q[1], acc1);
            acc2 = fmaf(w, (float)q[2], acc2);
        }
    }
    const float inv = 1.0f / ws;
    outb[pofs]             = acc0 * inv;
    outb[PLANE + pofs]     = acc1 * inv;
    outb[2 * PLANE + pofs] = acc2 * inv;
}

// launch_bounds (256,4): VGPR cap 128; row-pipelined version needs ~96-112.
// (256,8) forced 32 VGPRs -> 800MB scratch spill, 397us (R3). 2px/thread
// fully unrolled -> 1.7GB spill, 1117us (R4). Keep this shape.
__global__ __launch_bounds__(TX * TY, 4) void bilateral_kernel(const float* __restrict__ in,
                                                               float* __restrict__ out)
{
    __shared__ __align__(16) half8_t tile[NPOS];
    __shared__ float msk[NPOS];
    const int b = blockIdx.z;
    const int gx0 = blockIdx.x * TX;
    const int gy0 = blockIdx.y * TY;
    const float* inb = in + (size_t)b * CIN * PLANE;
    float* outb = out + (size_t)b * 3 * PLANE;

    const bool interior = (gx0 >= 3) && (gx0 + TX + 3 <= W) &&
                          (gy0 >= 3) && (gy0 + TY + 3 <= H);
    if (interior)
        run_tile<true>(inb, outb, tile, msk, gy0, gx0);
    else
        run_tile<false>(inb, outb, tile, msk, gy0, gx0);
}

} // namespace

extern "C" void kernel_launch(void* const* d_in, const int* in_sizes, int n_in,
                              void* d_out, int out_size, void* d_ws, size_t ws_size,
                              hipStream_t stream)
{
    const float* in = (const float*)d_in[0];
    float* out = (float*)d_out;
    dim3 grid(W / TX, H / TY, 2);
    dim3 block(TX, TY);
    hipLaunchKernelGGL(bilateral_kernel, grid, block, 0, stream, in, out);
}

// Round 2
// 254.701 us; speedup vs baseline: 3.9116x; 3.9116x over previous
//
#include <hip/hip_runtime.h>

namespace {

constexpr int H = 1024;
constexpr int W = 1024;
constexpr int PLANE = H * W;
constexpr int CIN = 18;     // total input channels
constexpr int C = 8;        // filterable channels
constexpr int TX = 16;
constexpr int TY = 16;
constexpr int SW = TX + 6;  // 22 halo tile width
constexpr int SH = TY + 6;  // 22 halo tile height
constexpr int NPOS = SW * SH;  // 484 positions
constexpr float LOG2E = 1.44269504088896340736f;

typedef _Float16 half2_t __attribute__((ext_vector_type(2)));
typedef _Float16 half8_t __attribute__((ext_vector_type(8)));

__device__ __forceinline__ float dot2acc(half2_t a, half2_t b, float c) {
#if defined(__has_builtin)
#if __has_builtin(__builtin_amdgcn_fdot2)
    return __builtin_amdgcn_fdot2(a, b, c, false);
#else
    return fmaf((float)a[0], (float)b[0], fmaf((float)a[1], (float)b[1], c));
#endif
#else
    return fmaf((float)a[0], (float)b[0], fmaf((float)a[1], (float)b[1], c));
#endif
}

__device__ __forceinline__ float fast_exp2(float x) {
#if defined(__has_builtin)
#if __has_builtin(__builtin_amdgcn_exp2f)
    return __builtin_amdgcn_exp2f(x);
#else
    return exp2f(x);
#endif
#else
    return exp2f(x);
#endif
}

template<bool INTERIOR>
__device__ __forceinline__ void run_tile(const float* __restrict__ inb,
                                         float* __restrict__ outb,
                                         half8_t* __restrict__ tile,
                                         float* __restrict__ msk,
                                         int gy0, int gx0)
{
    const int tx = threadIdx.x, ty = threadIdx.y;
    const int tid = ty * TX + tx;

    const int gy = gy0 + ty, gx = gx0 + tx;
    const int pofs = gy * W + gx;

    // ---- per-pixel params FIRST (before the barrier) so their global
    // latency overlaps the staging loop + barrier wait. log2e folded in.
    half2_t rp01, rp23, rp45, rp67;
    float sxf, syf;
    {
        const float* pp = inb + (size_t)C * PLANE + pofs;
        float r[C];
#pragma unroll
        for (int c = 0; c < C; ++c) {
            float p = pp[(size_t)c * PLANE];
            r[c] = -(p * p) * LOG2E;
        }
        float px_ = pp[(size_t)8 * PLANE];
        float py_ = pp[(size_t)9 * PLANE];
        rp01 = half2_t{(_Float16)r[0], (_Float16)r[1]};
        rp23 = half2_t{(_Float16)r[2], (_Float16)r[3]};
        rp45 = half2_t{(_Float16)r[4], (_Float16)r[5]};
        rp67 = half2_t{(_Float16)r[6], (_Float16)r[7]};
        sxf = -(px_ * px_) * LOG2E;
        syf = -(py_ * py_) * LOG2E;
    }

    // ---- stage: one 16B packed-f16 record per halo position ----
    for (int idx = tid; idx < NPOS; idx += TX * TY) {
        int y = idx / SW;
        int x = idx - y * SW;
        int sy_ = gy0 + y - 3;
        int sx_ = gx0 + x - 3;
        half8_t hv;
        if (INTERIOR || ((unsigned)sy_ < (unsigned)H && (unsigned)sx_ < (unsigned)W)) {
            const float* p = inb + sy_ * W + sx_;
#pragma unroll
            for (int c = 0; c < C; ++c) hv[c] = (_Float16)p[(size_t)c * PLANE];
            if (!INTERIOR) msk[idx] = 1.0f;
        } else {
#pragma unroll
            for (int c = 0; c < C; ++c) hv[c] = (_Float16)0.0f;
            msk[idx] = 0.0f;
        }
        tile[idx] = hv;
    }
    __syncthreads();

    const half8_t* lp = tile + ty * SW + tx;  // window origin for this pixel
    const half8_t fc = lp[3 * SW + 3];        // center (f16, so d==0 exactly)

    float acc0 = 0.f, acc1 = 0.f, acc2 = 0.f, ws = 0.f;

    // ---- software-pipelined rows with NAMED register sets (R1's array
    // ping-pong went to scratch: WRITE_SIZE 24MB->2GB, rule #20). Row i+1's
    // seven ds_read_b128 are issued before row i's compute consumes its set,
    // so ~7 LDS reads are always in flight under ~240 cycles of row compute.
    half8_t a0, a1, a2, a3, a4, a5, a6;
    half8_t b0, b1, b2, b3, b4, b5, b6;

#define LOAD_ROW(p0, p1, p2, p3, p4, p5, p6, I) do {                    \
        const half8_t* r_ = lp + (I) * SW;                              \
        p0 = r_[0]; p1 = r_[1]; p2 = r_[2]; p3 = r_[3];                 \
        p4 = r_[4]; p5 = r_[5]; p6 = r_[6];                             \
    } while (0)

#define PIX(Q, I, J) do {                                               \
        half8_t d_ = (Q) - fc;                                          \
        half8_t dd_ = d_ * d_;                                          \
        float lw_ = fmaf((float)(((J) - 3) * ((J) - 3)), sxf, rs_);     \
        lw_ = dot2acc(__builtin_shufflevector(dd_, dd_, 0, 1), rp01, lw_); \
        lw_ = dot2acc(__builtin_shufflevector(dd_, dd_, 2, 3), rp23, lw_); \
        lw_ = dot2acc(__builtin_shufflevector(dd_, dd_, 4, 5), rp45, lw_); \
        lw_ = dot2acc(__builtin_shufflevector(dd_, dd_, 6, 7), rp67, lw_); \
        float w_ = fast_exp2(lw_);                                      \
        if (!INTERIOR) w_ *= mrow_[(J)];                                \
        ws += w_;                                                       \
        acc0 = fmaf(w_, (float)(Q)[0], acc0);                           \
        acc1 = fmaf(w_, (float)(Q)[1], acc1);                           \
        acc2 = fmaf(w_, (float)(Q)[2], acc2);                           \
    } while (0)

#define ROW(p0, p1, p2, p3, p4, p5, p6, I) do {                         \
        const float rs_ = syf * (float)(((I) - 3) * ((I) - 3));         \
        const float* mrow_ = msk + (ty + (I)) * SW + tx;                \
        (void)mrow_;                                                    \
        PIX(p0, I, 0); PIX(p1, I, 1); PIX(p2, I, 2); PIX(p3, I, 3);     \
        PIX(p4, I, 4); PIX(p5, I, 5); PIX(p6, I, 6);                    \
    } while (0)

    LOAD_ROW(a0, a1, a2, a3, a4, a5, a6, 0);
    LOAD_ROW(b0, b1, b2, b3, b4, b5, b6, 1);
    ROW(a0, a1, a2, a3, a4, a5, a6, 0);
    LOAD_ROW(a0, a1, a2, a3, a4, a5, a6, 2);
    ROW(b0, b1, b2, b3, b4, b5, b6, 1);
    LOAD_ROW(b0, b1, b2, b3, b4, b5, b6, 3);
    ROW(a0, a1, a2, a3, a4, a5, a6, 2);
    LOAD_ROW(a0, a1, a2, a3, a4, a5, a6, 4);
    ROW(b0, b1, b2, b3, b4, b5, b6, 3);
    LOAD_ROW(b0, b1, b2, b3, b4, b5, b6, 5);
    ROW(a0, a1, a2, a3, a4, a5, a6, 4);
    LOAD_ROW(a0, a1, a2, a3, a4, a5, a6, 6);
    ROW(b0, b1, b2, b3, b4, b5, b6, 5);
    ROW(a0, a1, a2, a3, a4, a5, a6, 6);

#undef ROW
#undef PIX
#undef LOAD_ROW

    const float inv = 1.0f / ws;
    outb[pofs]             = acc0 * inv;
    outb[PLANE + pofs]     = acc1 * inv;
    outb[2 * PLANE + pofs] = acc2 * inv;
}

// launch_bounds (256,4): VGPR cap 128; named ping-pong needs ~110.
// (256,8) forced 32 VGPRs -> 800MB scratch spill, 397us (R3). 2px/thread
// fully unrolled -> 1.7GB spill, 1117us (R4). Array ping-pong -> scratch,
// 2GB writes, 845us/dispatch (R1/this session). Keep this shape.
__global__ __launch_bounds__(TX * TY, 4) void bilateral_kernel(const float* __restrict__ in,
                                                               float* __restrict__ out)
{
    __shared__ __align__(16) half8_t tile[NPOS];
    __shared__ float msk[NPOS];
    const int b = blockIdx.z;
    const int gx0 = blockIdx.x * TX;
    const int gy0 = blockIdx.y * TY;
    const float* inb = in + (size_t)b * CIN * PLANE;
    float* outb = out + (size_t)b * 3 * PLANE;

    const bool interior = (gx0 >= 3) && (gx0 + TX + 3 <= W) &&
                          (gy0 >= 3) && (gy0 + TY + 3 <= H);
    if (interior)
        run_tile<true>(inb, outb, tile, msk, gy0, gx0);
    else
        run_tile<false>(inb, outb, tile, msk, gy0, gx0);
}

} // namespace

extern "C" void kernel_launch(void* const* d_in, const int* in_sizes, int n_in,
                              void* d_out, int out_size, void* d_ws, size_t ws_size,
                              hipStream_t stream)
{
    const float* in = (const float*)d_in[0];
    float* out = (float*)d_out;
    dim3 grid(W / TX, H / TY, 2);
    dim3 block(TX, TY);
    hipLaunchKernelGGL(bilateral_kernel, grid, block, 0, stream, in, out);
}